// Round 6
// baseline (449.304 us; speedup 1.0000x reference)
//
#include <hip/hip_runtime.h>

// MultiBoxLoss_four_corners — B=64, P=8732, C=81, NEG_POS_RATIO=3
// Outputs: (loss_l/N, loss_c/N, loss_four_corners/N) -> d_out[0..2] (f32)
//
// R6: two-phase CE. Phase k_stream is copy-shaped (the only pattern measured
// fast on this machine: lane-consecutive float4 grid-stride, 6.8 TB/s fill
// evidence): reads conf as f4, writes one exp-sum per f4 to psum[] (45 MB),
// with row-boundary f4s (81 f4 = exactly 4 rows; splits at j=20/40/60) split
// into psum + splitB. Phase k_rows is R2-shaped (proven 108 us on 181 MB) on
// the 4x-smaller psum: thread-per-row sums 20-21 psums, log, gather, ce,
// batch atomics. LDS-tile structures (R3/R5: 233-270 us, latency-convoyed
// even when L3-resident) and scattered direct reads (R2/R4: ~110 us,
// ~20 in-flight lines/CU cap) are both abandoned for the heavy pass.

#define NB 64
#define NP 8732
#define NC 81
constexpr int BP   = NB * NP;              // 558848 rows
constexpr int NQ   = BP / 4;               // 139712 quads
constexpr int NF4  = NQ * 81;              // 11316672 float4s in conf
constexpr int G1   = 2048, B1 = 256;       // k_stream
constexpr int NT1  = G1 * B1;              // 524288
constexpr int G2   = BP / 256;             // 2183 blocks, exact

__device__ inline float sl1(float d) {
    d = fabsf(d);
    return d < 1.0f ? 0.5f * d * d : d - 0.5f;
}

// ws: ce[BP] | acc[64] (l:0..31,f:32..63) | gb[192] (sp|sn|np per batch)
//     | loss_c_b[64] | psum[NF4] | splitB[3*NQ]
__global__ void k_init(float* z) { z[threadIdx.x] = 0.0f; }   // acc+gb, 256

__global__ __launch_bounds__(B1) void k_stream(
    const float* __restrict__ conf_data, const float* __restrict__ loc_data,
    const float* __restrict__ loc_t,     const float* __restrict__ fc_data,
    const float* __restrict__ fc_t,      const int* __restrict__ conf_t,
    float* __restrict__ psum, float* __restrict__ splitB, float* __restrict__ acc)
{
    const int t    = threadIdx.x;
    const int lane = t & 63;
    const int gtid = blockIdx.x * B1 + t;
    const float4* cf4 = (const float4*)conf_data;

    // ---- conf exp partial sums: pure lane-consecutive stream ----
    for (int i = gtid; i < NF4; i += NT1) {
        float4 v = cf4[i];
        const unsigned q = (unsigned)(((unsigned long long)(unsigned)i * 3393554407ull) >> 38);
        const unsigned j = (unsigned)i - q * 81u;      // i % 81
        float ex = __expf(v.x), ey = __expf(v.y), ez = __expf(v.z), ew = __expf(v.w);
        float out;
        if (j == 20u)      { out = ex;           splitB[q * 3 + 0] = ey + ez + ew; }
        else if (j == 40u) { out = ex + ey;      splitB[q * 3 + 1] = ez + ew; }
        else if (j == 60u) { out = ex + ey + ez; splitB[q * 3 + 2] = ew; }
        else               { out = (ex + ey) + (ez + ew); }
        psum[i] = out;
    }

    // ---- loc/fc smooth-L1: coalesced grid-stride float4 (proven R4 form) ----
    float l_acc = 0.0f, f_acc = 0.0f;
    for (int i = gtid; i < BP; i += NT1) {             // loc: f4 index == row
        float4 a = ((const float4*)loc_data)[i];
        float4 b = ((const float4*)loc_t)[i];
        float m = (conf_t[i] > 0) ? 1.0f : 0.0f;
        l_acc += m * (sl1(a.x - b.x) + sl1(a.y - b.y) + sl1(a.z - b.z) + sl1(a.w - b.w));
    }
    for (int i = gtid; i < 2 * BP; i += NT1) {         // fc: row = i >> 1
        float4 a = ((const float4*)fc_data)[i];
        float4 b = ((const float4*)fc_t)[i];
        float m = (conf_t[i >> 1] > 0) ? 1.0f : 0.0f;
        f_acc += m * (sl1(a.x - b.x) + sl1(a.y - b.y) + sl1(a.z - b.z) + sl1(a.w - b.w));
    }
    #pragma unroll
    for (int o = 32; o; o >>= 1) {
        l_acc += __shfl_xor(l_acc, o, 64);
        f_acc += __shfl_xor(f_acc, o, 64);
    }
    if (lane == 0) {
        const int slot = blockIdx.x & 31;
        atomicAdd(&acc[slot],      l_acc);
        atomicAdd(&acc[32 + slot], f_acc);
    }
}

// thread-per-row over psum (R2 structure on 4x smaller data)
__global__ __launch_bounds__(256) void k_rows(
    const float* __restrict__ psum, const float* __restrict__ splitB,
    const float* __restrict__ conf_data, const int* __restrict__ conf_t,
    float* __restrict__ ce, float* __restrict__ gb)
{
    const int t    = threadIdx.x;
    const int lane = t & 63;
    const int r    = blockIdx.x * 256 + t;             // exact, no tail
    const int q    = r >> 2;
    const int rb   = r & 3;
    const int base = q * 81;

    // 21st term: psum[base+20] for rb==0 else splitB[3q+rb-1]
    const float* extp = (rb == 0) ? (psum + base + 20) : (splitB + 3 * q + rb - 1);
    float s = *extp;
    const float* pp = psum + base + 20 * rb + (rb != 0);
    float s0 = 0.f, s1 = 0.f, s2 = 0.f, s3 = 0.f;
    #pragma unroll
    for (int k = 0; k < 20; k += 4) {
        s0 += pp[k]; s1 += pp[k + 1]; s2 += pp[k + 2]; s3 += pp[k + 3];
    }
    s += (s0 + s1) + (s2 + s3);

    const int tgt = conf_t[r];
    const float cev = __logf(s) - conf_data[(size_t)r * NC + tgt];
    ce[r] = cev;

    // per-batch sums: wave spans at most 2 consecutive batches
    float sp = (tgt > 0) ? cev : 0.0f;
    float sn = cev - sp;
    float np = (tgt > 0) ? 1.0f : 0.0f;
    const int b_ = r / NP;
    const int b0 = __shfl(b_, 0, 64);
    const int bL = __shfl(b_, 63, 64);
    const float m0 = (b_ == b0) ? 1.f : 0.f;
    float sp0 = sp * m0, sp1 = sp - sp0;
    float sn0 = sn * m0, sn1 = sn - sn0;
    float np0 = np * m0, np1 = np - np0;
    #pragma unroll
    for (int o = 32; o; o >>= 1) {
        sp0 += __shfl_xor(sp0, o, 64);
        sp1 += __shfl_xor(sp1, o, 64);
        sn0 += __shfl_xor(sn0, o, 64);
        sn1 += __shfl_xor(sn1, o, 64);
        np0 += __shfl_xor(np0, o, 64);
        np1 += __shfl_xor(np1, o, 64);
    }
    if (lane == 0) {
        atomicAdd(&gb[b0],       sp0);
        atomicAdd(&gb[64 + b0],  sn0);
        atomicAdd(&gb[128 + b0], np0);
        if (bL != b0) {
            atomicAdd(&gb[bL],       sp1);
            atomicAdd(&gb[64 + bL],  sn1);
            atomicAdd(&gb[128 + bL], np1);
        }
    }
}

// One block per batch. Common path O(1); rare top-K via float-bit binary search.
__global__ __launch_bounds__(256) void k_batch(
    const float* __restrict__ ce, const int* __restrict__ conf_t,
    const float* __restrict__ gb, float* __restrict__ loss_c_b)
{
    const int b = blockIdx.x;
    const int t = threadIdx.x;
    const float spos = gb[b];
    const float sneg = gb[64 + b];
    const int npos    = (int)(gb[128 + b] + 0.5f);
    const int nneg    = NP - npos;
    const int num_neg = min(3 * npos, NP - 1);

    if (num_neg >= nneg) {                 // all negatives selected (this data)
        if (t == 0) loss_c_b[b] = spos + sneg;
        return;
    }
    if (num_neg <= 0) {
        if (t == 0) loss_c_b[b] = spos;
        return;
    }

    __shared__ float ce_s[NP];             // negative CE; positives -> -1
    __shared__ float sredf[4];
    __shared__ int   sredi[4];
    const float* crow = ce + (size_t)b * NP;
    const int*   trow = conf_t + (size_t)b * NP;
    for (int p = t; p < NP; p += 256)
        ce_s[p] = (trow[p] > 0) ? -1.0f : crow[p];
    __syncthreads();

    const int wave = t >> 6, lane = t & 63;
    const int K = num_neg;
    unsigned lo = 0u, hi = 0x7f800000u;
    while (lo < hi) {
        unsigned mid = lo + ((hi - lo) >> 1);
        float v = __uint_as_float(mid);
        int c_t = 0;
        for (int p = t; p < NP; p += 256) c_t += (ce_s[p] > v) ? 1 : 0;
        #pragma unroll
        for (int o = 32; o; o >>= 1) c_t += __shfl_xor(c_t, o, 64);
        __syncthreads();
        if (lane == 0) sredi[wave] = c_t;
        __syncthreads();
        int cnt = sredi[0] + sredi[1] + sredi[2] + sredi[3];
        if (cnt < K) hi = mid; else lo = mid + 1;
    }
    float v = __uint_as_float(lo);         // K-th largest negative CE
    int c_t = 0; float s_t = 0.0f;
    for (int p = t; p < NP; p += 256) {
        float x = ce_s[p];
        if (x > v) { c_t++; s_t += x; }
    }
    #pragma unroll
    for (int o = 32; o; o >>= 1) {
        c_t += __shfl_xor(c_t, o, 64);
        s_t += __shfl_xor(s_t, o, 64);
    }
    __syncthreads();
    if (lane == 0) { sredi[wave] = c_t; sredf[wave] = s_t; }
    __syncthreads();
    if (t == 0) {
        int   cnt = sredi[0] + sredi[1] + sredi[2] + sredi[3];
        float sgt = sredf[0] + sredf[1] + sredf[2] + sredf[3];
        loss_c_b[b] = spos + sgt + (float)(K - cnt) * v;
    }
}

__global__ void k_final(const float* __restrict__ acc,
                        const float* __restrict__ gb,
                        const float* __restrict__ loss_c_b,
                        float* __restrict__ out)
{
    const int t = threadIdx.x;             // 64
    const float av = acc[t];
    float a0 = (t < 32) ? av : 0.0f;       // l-slots
    float a1 = av - a0;                    // f-slots
    float lc = loss_c_b[t];
    float np = gb[128 + t];
    #pragma unroll
    for (int o = 32; o; o >>= 1) {
        a0 += __shfl_xor(a0, o, 64);
        a1 += __shfl_xor(a1, o, 64);
        lc += __shfl_xor(lc, o, 64);
        np += __shfl_xor(np, o, 64);
    }
    if (t == 0) {
        out[0] = a0 / np;
        out[1] = lc / np;
        out[2] = a1 / np;
    }
}

extern "C" void kernel_launch(void* const* d_in, const int* in_sizes, int n_in,
                              void* d_out, int out_size, void* d_ws, size_t ws_size,
                              hipStream_t stream)
{
    const float* loc_data  = (const float*)d_in[0];
    const float* conf_data = (const float*)d_in[1];
    const float* fc_data   = (const float*)d_in[2];
    const float* loc_t     = (const float*)d_in[3];
    const float* fc_t      = (const float*)d_in[4];
    const int*   conf_t    = (const int*)d_in[5];
    float* out = (float*)d_out;

    float* ce       = (float*)d_ws;
    float* acc      = ce + BP;             // [64]
    float* gb       = acc + 64;            // [192]
    float* loss_c_b = gb + 192;            // [64]
    float* psum     = loss_c_b + 64;       // [NF4]
    float* splitB   = psum + NF4;          // [3*NQ]

    hipLaunchKernelGGL(k_init,   dim3(1),  dim3(256), 0, stream, acc);
    hipLaunchKernelGGL(k_stream, dim3(G1), dim3(B1),  0, stream,
                       conf_data, loc_data, loc_t, fc_data, fc_t, conf_t,
                       psum, splitB, acc);
    hipLaunchKernelGGL(k_rows,   dim3(G2), dim3(256), 0, stream,
                       psum, splitB, conf_data, conf_t, ce, gb);
    hipLaunchKernelGGL(k_batch,  dim3(NB), dim3(256), 0, stream,
                       ce, conf_t, gb, loss_c_b);
    hipLaunchKernelGGL(k_final,  dim3(1),  dim3(64),  0, stream,
                       acc, gb, loss_c_b, out);
}